// Round 13
// baseline (392.571 us; speedup 1.0000x reference)
//
#include <hip/hip_runtime.h>

typedef __attribute__((ext_vector_type(8))) short bf16x8;
typedef __attribute__((ext_vector_type(4))) float f32x4;

constexpr int D = 64;
constexpr int SEG = 64;    // relation-segment padding granule = edges per wave
constexpr int CSTR = 16;   // counter stride (ints): 1 atomic counter per 64B line
constexpr int TSTR = 68;   // LDS tile row stride (floats): 2-way-free banks

__device__ inline unsigned short f2bf(float f) {  // RNE fp32->bf16
  unsigned u = __float_as_uint(f);
  u += 0x7fff + ((u >> 16) & 1);
  return (unsigned short)(u >> 16);
}
__device__ inline float bflo(unsigned u) { return __uint_as_float(u << 16); }
__device__ inline float bfhi(unsigned u) { return __uint_as_float(u & 0xffff0000u); }

// ---- counting: per-block relation histogram -> bcnt[r*nbE+b]; padded deg ----
__global__ __launch_bounds__(256) void count_kernel(
    const int* __restrict__ dst, const int* __restrict__ et,
    int* __restrict__ bcnt, int* __restrict__ deg, int E, int R, int nbE) {
  __shared__ int lh[128];
  int t = threadIdx.x;
  if (t < 128) lh[t] = 0;
  __syncthreads();
  int e = blockIdx.x * 256 + t;
  if (e < E) {
    atomicAdd(&deg[(long)dst[e] * CSTR], 1);   // one counter per cache line
    atomicAdd(&lh[et[e]], 1);
  }
  __syncthreads();
  if (t < R) bcnt[t * nbE + blockIdx.x] = lh[t];
}

// ---- dual-region 3-phase exclusive scan: bcnt (dense) + deg (strided) ----
__global__ __launch_bounds__(256) void scanA_dual_kernel(
    const int* __restrict__ bcnt, const int* __restrict__ deg,
    int* __restrict__ bsum, int nBC, int N, int nbBC) {
  __shared__ int s[256];
  int t = threadIdx.x;
  int b = blockIdx.x;
  int v;
  if (b < nbBC) {
    int i = b * 256 + t;
    v = (i < nBC) ? bcnt[i] : 0;
  } else {
    int i = (b - nbBC) * 256 + t;
    v = (i < N) ? deg[(long)i * CSTR] : 0;
  }
  s[t] = v;
  __syncthreads();
  for (int o = 128; o > 0; o >>= 1) {
    if (t < o) s[t] += s[t + o];
    __syncthreads();
  }
  if (t == 0) bsum[b] = s[0];
}

__device__ inline void scanB_region(int* bsum, int nb, int t) {
  __shared__ int s[256];
  __shared__ int carry;
  if (t == 0) carry = 0;
  __syncthreads();
  for (int base = 0; base < nb; base += 256) {
    int i = base + t;
    int v = (i < nb) ? bsum[i] : 0;
    s[t] = v;
    __syncthreads();
    for (int o = 1; o < 256; o <<= 1) {
      int u = (t >= o) ? s[t - o] : 0;
      __syncthreads();
      s[t] += u;
      __syncthreads();
    }
    if (i < nb) bsum[i] = carry + s[t] - v;   // exclusive
    __syncthreads();
    if (t == 0) carry += s[255];
    __syncthreads();
  }
}

__global__ __launch_bounds__(256) void scanB_dual_kernel(
    int* __restrict__ bsum, int nbBC, int nbN) {
  int t = threadIdx.x;
  scanB_region(bsum, nbBC, t);
  scanB_region(bsum + nbBC, nbN, t);
}

// blocks < nbBC: bcnt -> prefE (+ total); blocks >= nbBC: deg -> dstoff/cur2
__global__ __launch_bounds__(256) void scanC_dual_kernel(
    const int* __restrict__ bcnt, const int* __restrict__ deg,
    const int* __restrict__ bsum, int* __restrict__ prefE,
    int* __restrict__ dstoff, int* __restrict__ cur2,
    int nBC, int N, int nbBC) {
  __shared__ int s[256];
  int t = threadIdx.x;
  int b = blockIdx.x;
  bool isBC = (b < nbBC);
  int i = (isBC ? b : b - nbBC) * 256 + t;
  int n = isBC ? nBC : N;
  int v = 0;
  if (i < n) v = isBC ? bcnt[i] : deg[(long)i * CSTR];
  s[t] = v;
  __syncthreads();
  for (int o = 1; o < 256; o <<= 1) {
    int u = (t >= o) ? s[t - o] : 0;
    __syncthreads();
    s[t] += u;
    __syncthreads();
  }
  int excl = bsum[b] + s[t] - v;
  if (isBC) {
    if (i < n) prefE[i] = excl;
    if (i == n - 1) prefE[n] = excl + v;
  } else {
    if (i < n) { dstoff[i] = excl; cur2[(long)i * CSTR] = excl; }
    if (i == n - 1) dstoff[n] = excl + v;
  }
}

// ---- padded relation cursors + wave->relation table (merged) ----
__global__ void prefix_wrel_kernel(const int* __restrict__ prefE,
                                   int* __restrict__ cursor, int* __restrict__ wrel,
                                   int nbE, int R) {
  __shared__ int sc[128];
  int l = threadIdx.x;
  int c = 0;
  if (l < R) {
    int tot = prefE[(l + 1) * nbE] - prefE[l * nbE];
    c = (tot + SEG - 1) & ~(SEG - 1);
  }
  sc[l] = c;
  __syncthreads();
  for (int ofs = 1; ofs < 128; ofs <<= 1) {
    int v = (l >= ofs) ? sc[l - ofs] : 0;
    __syncthreads();
    sc[l] += v;
    __syncthreads();
  }
  if (l < R) {
    int cur = sc[l] - c;
    cursor[l] = cur;
    int w0 = cur >> 6;                       // padded segments are SEG-aligned
    int nw = c >> 6;
    for (int w = 0; w < nw; ++w) wrel[w0 + w] = l;
  }
}

// ---- counting-sort scatter: block bases precomputed; padded cur2 atomics ----
// eidx[pos]={src,jd}. Pads stay 0xFF (src=jd=-1). relrow written by msg L1.
__global__ __launch_bounds__(256) void scatter_kernel(
    const int* __restrict__ src, const int* __restrict__ dst, const int* __restrict__ et,
    const int* __restrict__ cursor, const int* __restrict__ prefE,
    int* __restrict__ cur2, int2* __restrict__ eidx,
    int E, int R, int nbE) {
  __shared__ int lh[128];
  __shared__ int lbase[128];
  int t = threadIdx.x, b = blockIdx.x;
  if (t < R) {
    lh[t] = 0;
    lbase[t] = cursor[t] + prefE[t * nbE + b] - prefE[t * nbE];
  }
  __syncthreads();
  int e = b * 256 + t;
  if (e < E) {
    int r = et[e], s = src[e], d = dst[e];
    int lr = atomicAdd(&lh[r], 1);               // within-block rank (LDS)
    int jd = atomicAdd(&cur2[(long)d * CSTR], 1); // own line -> pipelined RMW
    int pos = lbase[r] + lr;
    eidx[pos] = make_int2(s, jd);
  }
}

// ---- fused convert: xb + WT1 + WT2 + WTl1 + WTl2 in one launch ----
__global__ __launch_bounds__(256) void cvt_all_kernel(
    const float* __restrict__ x, unsigned short* __restrict__ xb, int nx,
    const float* __restrict__ W1, unsigned short* __restrict__ WT1,
    const float* __restrict__ W2, unsigned short* __restrict__ WT2, int nw,
    const float* __restrict__ Wl1, unsigned short* __restrict__ WTl1,
    const float* __restrict__ Wl2, unsigned short* __restrict__ WTl2, int nl) {
  int i = blockIdx.x * 256 + threadIdx.x;
  if (i < nx) { xb[i] = f2bf(x[i]); return; }
  i -= nx;
  if (i < 2 * nw) {
    const float* W = (i < nw) ? W1 : W2;
    unsigned short* WT = (i < nw) ? WT1 : WT2;
    int i2 = (i < nw) ? i : i - nw;
    int n = i2 & 63, k = (i2 >> 6) & 63, r = i2 >> 12;
    WT[(r << 12) + (n << 6) + k] = f2bf(W[(r << 12) + (k << 6) + n]);
    return;
  }
  i -= 2 * nw;
  if (i < 2 * nl) {
    const float* W = (i < nl) ? Wl1 : Wl2;
    unsigned short* WT = (i < nl) ? WTl1 : WTl2;
    int i2 = (i < nl) ? i : i - nl;
    int n = i2 & 63, k = (i2 >> 6) & 63;
    WT[(n << 6) + k] = f2bf(W[(k << 6) + n]);
  }
}

// ---- Phase A: MFMA matvec, stream raw msgs (round-11 config: capped, plain) ----
// msg row layout (32 dwords): dword o<16 = cols (o, o+16); o>=16 = cols (o+16, o+32).
__global__ __launch_bounds__(256) __attribute__((amdgpu_waves_per_eu(1, 4)))
void msg_kernel(const unsigned short* __restrict__ xb,
                const unsigned short* __restrict__ WT,
                const int2* __restrict__ eidx, const int* __restrict__ wrel,
                unsigned int* __restrict__ msgp, int* __restrict__ relrow, int nwaves) {
  const int lane = (int)threadIdx.x & 63;
  const int l15 = lane & 15;
  const int q = lane >> 4;
  const int wave = blockIdx.x * 4 + ((int)threadIdx.x >> 6);
  if (wave >= nwaves) return;
  const long base = (long)wave * SEG;
  const int r = wrel[wave];                 // wave-uniform relation (0 for pad tail)
  const unsigned short* wb = WT + ((long)r << 12);
  bf16x8 Bf[4][2];
#pragma unroll
  for (int nt = 0; nt < 4; ++nt)
#pragma unroll
    for (int kh = 0; kh < 2; ++kh)
      Bf[nt][kh] = *(const bf16x8*)(wb + (nt * 16 + l15) * 64 + kh * 32 + q * 8);
#pragma unroll
  for (int t = 0; t < 4; ++t) {
    int2 rec = eidx[base + t * 16 + l15];
    if (relrow && lane < 16 && rec.y >= 0) relrow[rec.y] = r;  // graph-invariant: L1 only
    const unsigned short* xr = xb + ((long)max(rec.x, 0) << 6);
    bf16x8 A0 = *(const bf16x8*)(xr + q * 8);
    bf16x8 A1 = *(const bf16x8*)(xr + 32 + q * 8);
    f32x4 acc0 = (f32x4)0.0f, acc1 = (f32x4)0.0f, acc2 = (f32x4)0.0f, acc3 = (f32x4)0.0f;
    acc0 = __builtin_amdgcn_mfma_f32_16x16x32_bf16(A0, Bf[0][0], acc0, 0, 0, 0);
    acc0 = __builtin_amdgcn_mfma_f32_16x16x32_bf16(A1, Bf[0][1], acc0, 0, 0, 0);
    acc1 = __builtin_amdgcn_mfma_f32_16x16x32_bf16(A0, Bf[1][0], acc1, 0, 0, 0);
    acc1 = __builtin_amdgcn_mfma_f32_16x16x32_bf16(A1, Bf[1][1], acc1, 0, 0, 0);
    acc2 = __builtin_amdgcn_mfma_f32_16x16x32_bf16(A0, Bf[2][0], acc2, 0, 0, 0);
    acc2 = __builtin_amdgcn_mfma_f32_16x16x32_bf16(A1, Bf[2][1], acc2, 0, 0, 0);
    acc3 = __builtin_amdgcn_mfma_f32_16x16x32_bf16(A0, Bf[3][0], acc3, 0, 0, 0);
    acc3 = __builtin_amdgcn_mfma_f32_16x16x32_bf16(A1, Bf[3][1], acc3, 0, 0, 0);
#pragma unroll
    for (int rg = 0; rg < 4; ++rg) {
      int row = q * 4 + rg;                  // C/D row = edge within tile
      int jd = __shfl(rec.y, row);           // dst-sorted msg row id (-1 = pad)
      if (jd >= 0) {
        unsigned p0 = (unsigned)f2bf(acc0[rg]) | ((unsigned)f2bf(acc1[rg]) << 16);
        unsigned p1 = (unsigned)f2bf(acc2[rg]) | ((unsigned)f2bf(acc3[rg]) << 16);
        unsigned int* mp = msgp + (long)jd * 32;
        mp[l15] = p0;
        mp[16 + l15] = p1;
      }
    }
  }
}

// ---- Fused Phase B + self-loop: wave aggregates 16 dsts into LDS tile, then
// runs the self-loop MFMA on its own 16 rows (A=xb, C=tile). No barrier needed:
// all producer/consumer traffic is within one wave. ----
__global__ __launch_bounds__(256) void aggself_kernel(
    const unsigned int* __restrict__ msgp, const int* __restrict__ dstoff,
    const int* __restrict__ relrow, const unsigned short* __restrict__ xbin,
    const unsigned short* __restrict__ WTl, float* __restrict__ out,
    unsigned short* __restrict__ hb, int N) {
  __shared__ float tile[4][16 * TSTR];   // per-wave 16x64 agg tile (padded rows)
  __shared__ int rsh[4][256];
  __shared__ float fsh[4][256];
  const int wv = (int)threadIdx.x >> 6;
  const int lane = (int)threadIdx.x & 63;
  const int j = lane & 31;
  const int half = lane >> 5;
  const int l15 = lane & 15;
  const int q = lane >> 4;
  const int base = blockIdx.x * 64 + wv * 16;   // this wave's 16 dst nodes
  // B fragments (Wl^T) — shared by all tiles
  bf16x8 Bf[4][2];
#pragma unroll
  for (int nt = 0; nt < 4; ++nt)
#pragma unroll
    for (int kh = 0; kh < 2; ++kh)
      Bf[nt][kh] = *(const bf16x8*)(WTl + (nt * 16 + l15) * 64 + kh * 32 + q * 8);
  if (base >= N) return;
  // ---- aggregate 16 dsts into the LDS tile ----
  for (int k = 0; k < 16; ++k) {
    int d = base + k;
    float aLo = 0.f, aHi = 0.f;
    if (d < N) {
      const int off = dstoff[d], end = dstoff[d + 1];
      const int deg = end - off;
      if (deg > 0 && deg <= 256) {
        const int nit = (deg + 63) >> 6;
        int cl[4];
        for (int it = 0; it < nit; ++it) {
          int l = it * 64 + lane;
          if (l < deg) rsh[wv][l] = relrow[off + l];
        }
        __threadfence_block();
        for (int it = 0; it < nit; ++it) {
          int l = it * 64 + lane;
          if (l < deg) {
            int rv = rsh[wv][l];
            int c = 0;
            for (int m = 0; m < deg; ++m) c += (rsh[wv][m] == rv) ? 1 : 0;
            cl[it] = c;
          }
        }
        for (int it = 0; it < nit; ++it) {
          int l = it * 64 + lane;
          if (l < deg) fsh[wv][l] = 1.0f / (float)cl[it];
        }
        __threadfence_block();
        float a0 = 0.f, a1 = 0.f, b0 = 0.f, b1 = 0.f;
        int i = off + half;
        for (; i + 2 < end; i += 4) {
          float w0 = fsh[wv][i - off];
          float w1 = fsh[wv][i + 2 - off];
          unsigned u0 = msgp[(long)i * 32 + j];
          unsigned u1 = msgp[(long)(i + 2) * 32 + j];
          a0 = fmaf(w0, bflo(u0), a0);
          a1 = fmaf(w0, bfhi(u0), a1);
          b0 = fmaf(w1, bflo(u1), b0);
          b1 = fmaf(w1, bfhi(u1), b1);
        }
        if (i < end) {
          float w0 = fsh[wv][i - off];
          unsigned u0 = msgp[(long)i * 32 + j];
          a0 = fmaf(w0, bflo(u0), a0);
          a1 = fmaf(w0, bfhi(u0), a1);
        }
        aLo = a0 + b0;
        aHi = a1 + b1;
      } else if (deg > 256) {
        for (int i = off + half; i < end; i += 2) {
          int rv = relrow[i];
          int c = 0;
          for (int m = off; m < end; ++m) c += (relrow[m] == rv) ? 1 : 0;
          float w = 1.0f / (float)c;
          unsigned u0 = msgp[(long)i * 32 + j];
          aLo = fmaf(w, bflo(u0), aLo);
          aHi = fmaf(w, bfhi(u0), aHi);
        }
      }
    }
    aLo += __shfl_xor(aLo, 32);
    aHi += __shfl_xor(aHi, 32);
    if (half == 0) {
      int colLo = (j < 16) ? j : j + 16;       // cols {0..15, 32..47}
      tile[wv][k * TSTR + colLo] = aLo;
      tile[wv][k * TSTR + colLo + 16] = aHi;   // cols {16..31, 48..63}
    }
  }
  __threadfence_block();
  // ---- self-loop MFMA on this wave's 16 rows ----
  const int m = min(base + l15, N - 1);
  const unsigned short* xr = xbin + ((long)m << 6);
  bf16x8 A0 = *(const bf16x8*)(xr + q * 8);
  bf16x8 A1 = *(const bf16x8*)(xr + 32 + q * 8);
  f32x4 acc[4];
#pragma unroll
  for (int nt = 0; nt < 4; ++nt) {
#pragma unroll
    for (int rg = 0; rg < 4; ++rg)
      acc[nt][rg] = tile[wv][(q * 4 + rg) * TSTR + nt * 16 + l15];
  }
#pragma unroll
  for (int nt = 0; nt < 4; ++nt) {
    acc[nt] = __builtin_amdgcn_mfma_f32_16x16x32_bf16(A0, Bf[nt][0], acc[nt], 0, 0, 0);
    acc[nt] = __builtin_amdgcn_mfma_f32_16x16x32_bf16(A1, Bf[nt][1], acc[nt], 0, 0, 0);
  }
#pragma unroll
  for (int rg = 0; rg < 4; ++rg) {
    int node = base + q * 4 + rg;
    if (node < N) {
#pragma unroll
      for (int nt = 0; nt < 4; ++nt) {
        float v = fmaxf(acc[nt][rg], 0.0f);
        out[(long)node * D + nt * 16 + l15] = v;
        if (hb) hb[(long)node * D + nt * 16 + l15] = f2bf(v);
      }
    }
  }
}

extern "C" void kernel_launch(void* const* d_in, const int* in_sizes, int n_in,
                              void* d_out, int out_size, void* d_ws, size_t ws_size,
                              hipStream_t stream) {
  const float* x   = (const float*)d_in[0];
  const int* src   = (const int*)d_in[1];
  const int* dst   = (const int*)d_in[2];
  const int* et    = (const int*)d_in[3];
  const float* W1  = (const float*)d_in[4];
  const float* Wl1 = (const float*)d_in[5];
  const float* W2  = (const float*)d_in[6];
  const float* Wl2 = (const float*)d_in[7];
  float* out = (float*)d_out;

  const int N = in_sizes[0] / D;
  const int E = in_sizes[1];
  const int R = in_sizes[4] / (D * D);

  const int Ecap = ((E + SEG - 1) & ~(SEG - 1)) + R * SEG;
  const int nwaves = Ecap / SEG;
  const int nbN = (N + 255) / 256;          // blocks over nodes
  const int nbE = (E + 255) / 256;          // blocks over edges
  const int nBC = R * nbE;                  // bcnt length
  const int nbBC = (nBC + 255) / 256;       // scan blocks over bcnt

  char* ws = (char*)d_ws;
  size_t off = 0;
  auto alloc = [&](size_t bytes) -> void* {
    void* p = (void*)(ws + off);
    off += (bytes + 255) & ~(size_t)255;
    return p;
  };
  int*   cursor = (int*)alloc((size_t)R * sizeof(int));
  int*   deg    = (int*)alloc((size_t)N * CSTR * sizeof(int));   // padded: 1/line
  int*   cur2   = (int*)alloc((size_t)N * CSTR * sizeof(int));   // padded: 1/line
  int*   bcnt   = (int*)alloc((size_t)nBC * sizeof(int));
  int*   prefE  = (int*)alloc((size_t)(nBC + 1) * sizeof(int));
  int*   bsum   = (int*)alloc((size_t)(nbBC + nbN) * sizeof(int));
  int*   dstoff = (int*)alloc((size_t)(N + 1) * sizeof(int));
  int*   relrow = (int*)alloc((size_t)E * sizeof(int));
  int*   wrel   = (int*)alloc((size_t)nwaves * sizeof(int));
  int2*  eidx   = (int2*)alloc((size_t)(Ecap + SEG) * sizeof(int2));
  unsigned int* msgp = (unsigned int*)alloc((size_t)E * 32 * sizeof(unsigned int));
  unsigned short* xb  = (unsigned short*)alloc((size_t)N * D * sizeof(unsigned short));
  unsigned short* hb  = (unsigned short*)alloc((size_t)N * D * sizeof(unsigned short));
  unsigned short* WT1 = (unsigned short*)alloc((size_t)R * D * D * sizeof(unsigned short));
  unsigned short* WT2 = (unsigned short*)alloc((size_t)R * D * D * sizeof(unsigned short));
  unsigned short* WTl1 = (unsigned short*)alloc((size_t)D * D * sizeof(unsigned short));
  unsigned short* WTl2 = (unsigned short*)alloc((size_t)D * D * sizeof(unsigned short));
  (void)ws_size; (void)n_in; (void)out_size;

  const int msg_blocks = (nwaves + 3) / 4;
  const int as_blocks = (N + 63) / 64;
  const int nx = N * D;
  const int nw = R * D * D;
  const int nl = D * D;
  const int cvt_total = nx + 2 * nw + 2 * nl;

  // ---- shared preprocessing ----
  hipMemsetAsync(deg, 0, (size_t)N * CSTR * sizeof(int), stream);
  hipMemsetAsync(wrel, 0, (size_t)nwaves * sizeof(int), stream);
  hipMemsetAsync(eidx, 0xFF, (size_t)(Ecap + SEG) * sizeof(int2), stream);
  count_kernel<<<nbE, 256, 0, stream>>>(dst, et, bcnt, deg, E, R, nbE);
  scanA_dual_kernel<<<nbBC + nbN, 256, 0, stream>>>(bcnt, deg, bsum, nBC, N, nbBC);
  scanB_dual_kernel<<<1, 256, 0, stream>>>(bsum, nbBC, nbN);
  scanC_dual_kernel<<<nbBC + nbN, 256, 0, stream>>>(bcnt, deg, bsum, prefE,
                                                    dstoff, cur2, nBC, N, nbBC);
  prefix_wrel_kernel<<<1, 128, 0, stream>>>(prefE, cursor, wrel, nbE, R);
  scatter_kernel<<<nbE, 256, 0, stream>>>(src, dst, et, cursor, prefE, cur2,
                                          eidx, E, R, nbE);
  cvt_all_kernel<<<(cvt_total + 255) / 256, 256, 0, stream>>>(
      x, xb, nx, W1, WT1, W2, WT2, nw, Wl1, WTl1, Wl2, WTl2, nl);

  // ---- layer 1 (msg also writes graph-invariant relrow) ----
  msg_kernel<<<msg_blocks, 256, 0, stream>>>(xb, WT1, eidx, wrel, msgp, relrow, nwaves);
  aggself_kernel<<<as_blocks, 256, 0, stream>>>(msgp, dstoff, relrow, xb, WTl1,
                                                out, hb, N);
  // ---- layer 2 (relrow already valid: skip) ----
  msg_kernel<<<msg_blocks, 256, 0, stream>>>(hb, WT2, eidx, wrel, msgp, nullptr, nwaves);
  aggself_kernel<<<as_blocks, 256, 0, stream>>>(msgp, dstoff, relrow, hb, WTl2,
                                                out, nullptr, N);
}

// Round 14
// 337.321 us; speedup vs baseline: 1.1638x; 1.1638x over previous
//
#include <hip/hip_runtime.h>

typedef __attribute__((ext_vector_type(8))) short bf16x8;
typedef __attribute__((ext_vector_type(4))) float f32x4;

constexpr int D = 64;
constexpr int SEG = 64;    // relation-segment padding granule = edges per wave
constexpr int CSTR = 16;   // counter stride (ints): 1 atomic counter per 64B line

__device__ inline unsigned short f2bf(float f) {  // RNE fp32->bf16
  unsigned u = __float_as_uint(f);
  u += 0x7fff + ((u >> 16) & 1);
  return (unsigned short)(u >> 16);
}
__device__ inline float bflo(unsigned u) { return __uint_as_float(u << 16); }
__device__ inline float bfhi(unsigned u) { return __uint_as_float(u & 0xffff0000u); }

// ---- counting: per-block relation histogram -> bcnt[r*nbE+b]; padded deg ----
__global__ __launch_bounds__(256) void count_kernel(
    const int* __restrict__ dst, const int* __restrict__ et,
    int* __restrict__ bcnt, int* __restrict__ deg, int E, int R, int nbE) {
  __shared__ int lh[128];
  int t = threadIdx.x;
  if (t < 128) lh[t] = 0;
  __syncthreads();
  int e = blockIdx.x * 256 + t;
  if (e < E) {
    atomicAdd(&deg[(long)dst[e] * CSTR], 1);   // one counter per cache line
    atomicAdd(&lh[et[e]], 1);
  }
  __syncthreads();
  if (t < R) bcnt[t * nbE + blockIdx.x] = lh[t];
}

// ---- dual-region 3-phase exclusive scan: bcnt (dense) + deg (strided) ----
__global__ __launch_bounds__(256) void scanA_dual_kernel(
    const int* __restrict__ bcnt, const int* __restrict__ deg,
    int* __restrict__ bsum, int nBC, int N, int nbBC) {
  __shared__ int s[256];
  int t = threadIdx.x;
  int b = blockIdx.x;
  int v;
  if (b < nbBC) {
    int i = b * 256 + t;
    v = (i < nBC) ? bcnt[i] : 0;
  } else {
    int i = (b - nbBC) * 256 + t;
    v = (i < N) ? deg[(long)i * CSTR] : 0;
  }
  s[t] = v;
  __syncthreads();
  for (int o = 128; o > 0; o >>= 1) {
    if (t < o) s[t] += s[t + o];
    __syncthreads();
  }
  if (t == 0) bsum[b] = s[0];
}

__device__ inline void scanB_region(int* bsum, int nb, int t) {
  __shared__ int s[256];
  __shared__ int carry;
  if (t == 0) carry = 0;
  __syncthreads();
  for (int base = 0; base < nb; base += 256) {
    int i = base + t;
    int v = (i < nb) ? bsum[i] : 0;
    s[t] = v;
    __syncthreads();
    for (int o = 1; o < 256; o <<= 1) {
      int u = (t >= o) ? s[t - o] : 0;
      __syncthreads();
      s[t] += u;
      __syncthreads();
    }
    if (i < nb) bsum[i] = carry + s[t] - v;   // exclusive
    __syncthreads();
    if (t == 0) carry += s[255];
    __syncthreads();
  }
}

__global__ __launch_bounds__(256) void scanB_dual_kernel(
    int* __restrict__ bsum, int nbBC, int nbN) {
  int t = threadIdx.x;
  scanB_region(bsum, nbBC, t);
  scanB_region(bsum + nbBC, nbN, t);
}

// blocks < nbBC: bcnt -> prefE (+ total); blocks >= nbBC: deg -> dstoff/cur2
__global__ __launch_bounds__(256) void scanC_dual_kernel(
    const int* __restrict__ bcnt, const int* __restrict__ deg,
    const int* __restrict__ bsum, int* __restrict__ prefE,
    int* __restrict__ dstoff, int* __restrict__ cur2,
    int nBC, int N, int nbBC) {
  __shared__ int s[256];
  int t = threadIdx.x;
  int b = blockIdx.x;
  bool isBC = (b < nbBC);
  int i = (isBC ? b : b - nbBC) * 256 + t;
  int n = isBC ? nBC : N;
  int v = 0;
  if (i < n) v = isBC ? bcnt[i] : deg[(long)i * CSTR];
  s[t] = v;
  __syncthreads();
  for (int o = 1; o < 256; o <<= 1) {
    int u = (t >= o) ? s[t - o] : 0;
    __syncthreads();
    s[t] += u;
    __syncthreads();
  }
  int excl = bsum[b] + s[t] - v;
  if (isBC) {
    if (i < n) prefE[i] = excl;
    if (i == n - 1) prefE[n] = excl + v;
  } else {
    if (i < n) { dstoff[i] = excl; cur2[(long)i * CSTR] = excl; }
    if (i == n - 1) dstoff[n] = excl + v;
  }
}

// ---- padded relation cursors + wave->relation table (merged) ----
__global__ void prefix_wrel_kernel(const int* __restrict__ prefE,
                                   int* __restrict__ cursor, int* __restrict__ wrel,
                                   int nbE, int R) {
  __shared__ int sc[128];
  int l = threadIdx.x;
  int c = 0;
  if (l < R) {
    int tot = prefE[(l + 1) * nbE] - prefE[l * nbE];
    c = (tot + SEG - 1) & ~(SEG - 1);
  }
  sc[l] = c;
  __syncthreads();
  for (int ofs = 1; ofs < 128; ofs <<= 1) {
    int v = (l >= ofs) ? sc[l - ofs] : 0;
    __syncthreads();
    sc[l] += v;
    __syncthreads();
  }
  if (l < R) {
    int cur = sc[l] - c;
    cursor[l] = cur;
    int w0 = cur >> 6;                       // padded segments are SEG-aligned
    int nw = c >> 6;
    for (int w = 0; w < nw; ++w) wrel[w0 + w] = l;
  }
}

// ---- counting-sort scatter: block bases precomputed; padded cur2 atomics ----
// eidx[pos]={src,jd}. Pads stay 0xFF (src=jd=-1). relrow written by msg L1.
__global__ __launch_bounds__(256) void scatter_kernel(
    const int* __restrict__ src, const int* __restrict__ dst, const int* __restrict__ et,
    const int* __restrict__ cursor, const int* __restrict__ prefE,
    int* __restrict__ cur2, int2* __restrict__ eidx,
    int E, int R, int nbE) {
  __shared__ int lh[128];
  __shared__ int lbase[128];
  int t = threadIdx.x, b = blockIdx.x;
  if (t < R) {
    lh[t] = 0;
    lbase[t] = cursor[t] + prefE[t * nbE + b] - prefE[t * nbE];
  }
  __syncthreads();
  int e = b * 256 + t;
  if (e < E) {
    int r = et[e], s = src[e], d = dst[e];
    int lr = atomicAdd(&lh[r], 1);               // within-block rank (LDS)
    int jd = atomicAdd(&cur2[(long)d * CSTR], 1); // own line -> pipelined RMW
    int pos = lbase[r] + lr;
    eidx[pos] = make_int2(s, jd);
  }
}

// ---- fused convert: xb + WT1 + WT2 + WTl1 + WTl2 in one launch ----
__global__ __launch_bounds__(256) void cvt_all_kernel(
    const float* __restrict__ x, unsigned short* __restrict__ xb, int nx,
    const float* __restrict__ W1, unsigned short* __restrict__ WT1,
    const float* __restrict__ W2, unsigned short* __restrict__ WT2, int nw,
    const float* __restrict__ Wl1, unsigned short* __restrict__ WTl1,
    const float* __restrict__ Wl2, unsigned short* __restrict__ WTl2, int nl) {
  int i = blockIdx.x * 256 + threadIdx.x;
  if (i < nx) { xb[i] = f2bf(x[i]); return; }
  i -= nx;
  if (i < 2 * nw) {
    const float* W = (i < nw) ? W1 : W2;
    unsigned short* WT = (i < nw) ? WT1 : WT2;
    int i2 = (i < nw) ? i : i - nw;
    int n = i2 & 63, k = (i2 >> 6) & 63, r = i2 >> 12;
    WT[(r << 12) + (n << 6) + k] = f2bf(W[(r << 12) + (k << 6) + n]);
    return;
  }
  i -= 2 * nw;
  if (i < 2 * nl) {
    const float* W = (i < nl) ? Wl1 : Wl2;
    unsigned short* WT = (i < nl) ? WTl1 : WTl2;
    int i2 = (i < nl) ? i : i - nl;
    int n = i2 & 63, k = (i2 >> 6) & 63;
    WT[(n << 6) + k] = f2bf(W[(k << 6) + n]);
  }
}

// ---- Phase A: MFMA matvec, stream raw msgs (plain stores, uncapped occ) ----
// msg row layout (32 dwords): dword o<16 = cols (o, o+16); o>=16 = cols (o+16, o+32).
__global__ __launch_bounds__(256)
void msg_kernel(const unsigned short* __restrict__ xb,
                const unsigned short* __restrict__ WT,
                const int2* __restrict__ eidx, const int* __restrict__ wrel,
                unsigned int* __restrict__ msgp, int* __restrict__ relrow, int nwaves) {
  const int lane = (int)threadIdx.x & 63;
  const int l15 = lane & 15;
  const int q = lane >> 4;
  const int wave = blockIdx.x * 4 + ((int)threadIdx.x >> 6);
  if (wave >= nwaves) return;
  const long base = (long)wave * SEG;
  const int r = wrel[wave];                 // wave-uniform relation (0 for pad tail)
  const unsigned short* wb = WT + ((long)r << 12);
  bf16x8 Bf[4][2];
#pragma unroll
  for (int nt = 0; nt < 4; ++nt)
#pragma unroll
    for (int kh = 0; kh < 2; ++kh)
      Bf[nt][kh] = *(const bf16x8*)(wb + (nt * 16 + l15) * 64 + kh * 32 + q * 8);
#pragma unroll
  for (int t = 0; t < 4; ++t) {
    int2 rec = eidx[base + t * 16 + l15];
    if (relrow && lane < 16 && rec.y >= 0) relrow[rec.y] = r;  // graph-invariant: L1 only
    const unsigned short* xr = xb + ((long)max(rec.x, 0) << 6);
    bf16x8 A0 = *(const bf16x8*)(xr + q * 8);
    bf16x8 A1 = *(const bf16x8*)(xr + 32 + q * 8);
    f32x4 acc0 = (f32x4)0.0f, acc1 = (f32x4)0.0f, acc2 = (f32x4)0.0f, acc3 = (f32x4)0.0f;
    acc0 = __builtin_amdgcn_mfma_f32_16x16x32_bf16(A0, Bf[0][0], acc0, 0, 0, 0);
    acc0 = __builtin_amdgcn_mfma_f32_16x16x32_bf16(A1, Bf[0][1], acc0, 0, 0, 0);
    acc1 = __builtin_amdgcn_mfma_f32_16x16x32_bf16(A0, Bf[1][0], acc1, 0, 0, 0);
    acc1 = __builtin_amdgcn_mfma_f32_16x16x32_bf16(A1, Bf[1][1], acc1, 0, 0, 0);
    acc2 = __builtin_amdgcn_mfma_f32_16x16x32_bf16(A0, Bf[2][0], acc2, 0, 0, 0);
    acc2 = __builtin_amdgcn_mfma_f32_16x16x32_bf16(A1, Bf[2][1], acc2, 0, 0, 0);
    acc3 = __builtin_amdgcn_mfma_f32_16x16x32_bf16(A0, Bf[3][0], acc3, 0, 0, 0);
    acc3 = __builtin_amdgcn_mfma_f32_16x16x32_bf16(A1, Bf[3][1], acc3, 0, 0, 0);
#pragma unroll
    for (int rg = 0; rg < 4; ++rg) {
      int row = q * 4 + rg;                  // C/D row = edge within tile
      int jd = __shfl(rec.y, row);           // dst-sorted msg row id (-1 = pad)
      if (jd >= 0) {
        unsigned p0 = (unsigned)f2bf(acc0[rg]) | ((unsigned)f2bf(acc1[rg]) << 16);
        unsigned p1 = (unsigned)f2bf(acc2[rg]) | ((unsigned)f2bf(acc3[rg]) << 16);
        unsigned int* mp = msgp + (long)jd * 32;
        mp[l15] = p0;
        mp[16 + l15] = p1;
      }
    }
  }
}

// ---- weight precompute (once per graph): wrow[jd] = 1/cnt(dst,rel) ----
// Wave per dst: stage rel values in LDS, count equal-rel matches.
__global__ __launch_bounds__(256) void weight_kernel(
    const int* __restrict__ relrow, const int* __restrict__ dstoff,
    float* __restrict__ wrow, int N) {
  __shared__ int rsh[4][256];
  const int wv = (int)threadIdx.x >> 6;
  const int lane = (int)threadIdx.x & 63;
  const int d = blockIdx.x * 4 + wv;
  if (d >= N) return;
  const int off = dstoff[d], end = dstoff[d + 1];
  const int deg = end - off;
  if (deg <= 0) return;
  if (deg <= 256) {
    const int nit = (deg + 63) >> 6;
    for (int it = 0; it < nit; ++it) {
      int l = it * 64 + lane;
      if (l < deg) rsh[wv][l] = relrow[off + l];
    }
    __threadfence_block();
    for (int it = 0; it < nit; ++it) {
      int l = it * 64 + lane;
      if (l < deg) {
        int rv = rsh[wv][l];
        int c = 0;
        for (int m = 0; m < deg; ++m) c += (rsh[wv][m] == rv) ? 1 : 0;
        wrow[off + l] = 1.0f / (float)c;
      }
    }
  } else {
    for (int l = lane; l < deg; l += 64) {
      int rv = relrow[off + l];
      int c = 0;
      for (int m = off; m < end; ++m) c += (relrow[m] == rv) ? 1 : 0;
      wrow[off + l] = 1.0f / (float)c;
    }
  }
}

// ---- Phase B (slim): wave per dst; pure streaming weighted accumulate ----
__global__ __launch_bounds__(256) void agg_kernel(
    const unsigned int* __restrict__ msgp, const int* __restrict__ dstoff,
    const float* __restrict__ wrow, float* __restrict__ agg, int N) {
  const int lane = (int)threadIdx.x & 63;
  const int j = lane & 31;
  const int half = lane >> 5;
  const int d = blockIdx.x * 4 + ((int)threadIdx.x >> 6);
  if (d >= N) return;
  const int off = dstoff[d], end = dstoff[d + 1];
  float a0 = 0.f, a1 = 0.f, b0 = 0.f, b1 = 0.f;
  int i = off + half;
  for (; i + 2 < end; i += 4) {
    float w0 = wrow[i];
    float w1 = wrow[i + 2];
    unsigned u0 = msgp[(long)i * 32 + j];
    unsigned u1 = msgp[(long)(i + 2) * 32 + j];
    a0 = fmaf(w0, bflo(u0), a0);
    a1 = fmaf(w0, bfhi(u0), a1);
    b0 = fmaf(w1, bflo(u1), b0);
    b1 = fmaf(w1, bfhi(u1), b1);
  }
  if (i < end) {
    float w0 = wrow[i];
    unsigned u0 = msgp[(long)i * 32 + j];
    a0 = fmaf(w0, bflo(u0), a0);
    a1 = fmaf(w0, bfhi(u0), a1);
  }
  float aLo = a0 + b0, aHi = a1 + b1;
  aLo += __shfl_xor(aLo, 32);
  aHi += __shfl_xor(aHi, 32);
  if (half == 0) {
    int colLo = (j < 16) ? j : j + 16;       // cols {0..15, 32..47}
    agg[(long)d * D + colLo] = aLo;
    agg[(long)d * D + colLo + 16] = aHi;     // cols {16..31, 48..63}
  }
}

// ---- self-loop as MFMA GEMM: out = relu(agg + xb @ Wl), agg as C-operand ----
__global__ __launch_bounds__(256) void selfloop_kernel(
    const unsigned short* __restrict__ xbin, const unsigned short* __restrict__ WTl,
    const float* __restrict__ agg, float* __restrict__ out,
    unsigned short* __restrict__ hb, int N) {
  const int lane = (int)threadIdx.x & 63;
  const int l15 = lane & 15;
  const int q = lane >> 4;
  const int wave = blockIdx.x * 4 + ((int)threadIdx.x >> 6);
  const int base = wave * 64;
  if (base >= N) return;
  bf16x8 Bf[4][2];
#pragma unroll
  for (int nt = 0; nt < 4; ++nt)
#pragma unroll
    for (int kh = 0; kh < 2; ++kh)
      Bf[nt][kh] = *(const bf16x8*)(WTl + (nt * 16 + l15) * 64 + kh * 32 + q * 8);
#pragma unroll
  for (int t = 0; t < 4; ++t) {
    const int row0 = base + t * 16;
    if (row0 >= N) break;
    const int m = min(row0 + l15, N - 1);
    const unsigned short* xr = xbin + ((long)m << 6);
    bf16x8 A0 = *(const bf16x8*)(xr + q * 8);
    bf16x8 A1 = *(const bf16x8*)(xr + 32 + q * 8);
    f32x4 acc[4];
#pragma unroll
    for (int nt = 0; nt < 4; ++nt) {
#pragma unroll
      for (int rg = 0; rg < 4; ++rg) {
        int node = row0 + q * 4 + rg;
        acc[nt][rg] = (node < N) ? agg[(long)node * D + nt * 16 + l15] : 0.0f;
      }
    }
#pragma unroll
    for (int nt = 0; nt < 4; ++nt) {
      acc[nt] = __builtin_amdgcn_mfma_f32_16x16x32_bf16(A0, Bf[nt][0], acc[nt], 0, 0, 0);
      acc[nt] = __builtin_amdgcn_mfma_f32_16x16x32_bf16(A1, Bf[nt][1], acc[nt], 0, 0, 0);
    }
#pragma unroll
    for (int rg = 0; rg < 4; ++rg) {
      int node = row0 + q * 4 + rg;
      if (node < N) {
#pragma unroll
        for (int nt = 0; nt < 4; ++nt) {
          float v = fmaxf(acc[nt][rg], 0.0f);
          out[(long)node * D + nt * 16 + l15] = v;
          if (hb) hb[(long)node * D + nt * 16 + l15] = f2bf(v);
        }
      }
    }
  }
}

extern "C" void kernel_launch(void* const* d_in, const int* in_sizes, int n_in,
                              void* d_out, int out_size, void* d_ws, size_t ws_size,
                              hipStream_t stream) {
  const float* x   = (const float*)d_in[0];
  const int* src   = (const int*)d_in[1];
  const int* dst   = (const int*)d_in[2];
  const int* et    = (const int*)d_in[3];
  const float* W1  = (const float*)d_in[4];
  const float* Wl1 = (const float*)d_in[5];
  const float* W2  = (const float*)d_in[6];
  const float* Wl2 = (const float*)d_in[7];
  float* out = (float*)d_out;

  const int N = in_sizes[0] / D;
  const int E = in_sizes[1];
  const int R = in_sizes[4] / (D * D);

  const int Ecap = ((E + SEG - 1) & ~(SEG - 1)) + R * SEG;
  const int nwaves = Ecap / SEG;
  const int nbN = (N + 255) / 256;          // blocks over nodes
  const int nbE = (E + 255) / 256;          // blocks over edges
  const int nBC = R * nbE;                  // bcnt length
  const int nbBC = (nBC + 255) / 256;       // scan blocks over bcnt

  char* ws = (char*)d_ws;
  size_t off = 0;
  auto alloc = [&](size_t bytes) -> void* {
    void* p = (void*)(ws + off);
    off += (bytes + 255) & ~(size_t)255;
    return p;
  };
  int*   cursor = (int*)alloc((size_t)R * sizeof(int));
  int*   deg    = (int*)alloc((size_t)N * CSTR * sizeof(int));   // padded: 1/line
  int*   cur2   = (int*)alloc((size_t)N * CSTR * sizeof(int));   // padded: 1/line
  int*   bcnt   = (int*)alloc((size_t)nBC * sizeof(int));
  int*   prefE  = (int*)alloc((size_t)(nBC + 1) * sizeof(int));
  int*   bsum   = (int*)alloc((size_t)(nbBC + nbN) * sizeof(int));
  int*   dstoff = (int*)alloc((size_t)(N + 1) * sizeof(int));
  int*   relrow = (int*)alloc((size_t)E * sizeof(int));
  float* wrow   = (float*)alloc((size_t)E * sizeof(float));
  int*   wrel   = (int*)alloc((size_t)nwaves * sizeof(int));
  int2*  eidx   = (int2*)alloc((size_t)(Ecap + SEG) * sizeof(int2));
  unsigned int* msgp = (unsigned int*)alloc((size_t)E * 32 * sizeof(unsigned int));
  float* agg    = (float*)alloc((size_t)N * D * sizeof(float));
  unsigned short* xb  = (unsigned short*)alloc((size_t)N * D * sizeof(unsigned short));
  unsigned short* hb  = (unsigned short*)alloc((size_t)N * D * sizeof(unsigned short));
  unsigned short* WT1 = (unsigned short*)alloc((size_t)R * D * D * sizeof(unsigned short));
  unsigned short* WT2 = (unsigned short*)alloc((size_t)R * D * D * sizeof(unsigned short));
  unsigned short* WTl1 = (unsigned short*)alloc((size_t)D * D * sizeof(unsigned short));
  unsigned short* WTl2 = (unsigned short*)alloc((size_t)D * D * sizeof(unsigned short));
  (void)ws_size; (void)n_in; (void)out_size;

  const int msg_blocks = (nwaves + 3) / 4;
  const int agg_blocks = (N + 3) / 4;
  const int sl_blocks = ((N + 63) / 64 + 3) / 4;
  const int nx = N * D;
  const int nw = R * D * D;
  const int nl = D * D;
  const int cvt_total = nx + 2 * nw + 2 * nl;

  // ---- shared preprocessing ----
  hipMemsetAsync(deg, 0, (size_t)N * CSTR * sizeof(int), stream);
  hipMemsetAsync(wrel, 0, (size_t)nwaves * sizeof(int), stream);
  hipMemsetAsync(eidx, 0xFF, (size_t)(Ecap + SEG) * sizeof(int2), stream);
  count_kernel<<<nbE, 256, 0, stream>>>(dst, et, bcnt, deg, E, R, nbE);
  scanA_dual_kernel<<<nbBC + nbN, 256, 0, stream>>>(bcnt, deg, bsum, nBC, N, nbBC);
  scanB_dual_kernel<<<1, 256, 0, stream>>>(bsum, nbBC, nbN);
  scanC_dual_kernel<<<nbBC + nbN, 256, 0, stream>>>(bcnt, deg, bsum, prefE,
                                                    dstoff, cur2, nBC, N, nbBC);
  prefix_wrel_kernel<<<1, 128, 0, stream>>>(prefE, cursor, wrel, nbE, R);
  scatter_kernel<<<nbE, 256, 0, stream>>>(src, dst, et, cursor, prefE, cur2,
                                          eidx, E, R, nbE);
  cvt_all_kernel<<<(cvt_total + 255) / 256, 256, 0, stream>>>(
      x, xb, nx, W1, WT1, W2, WT2, nw, Wl1, WTl1, Wl2, WTl2, nl);

  // ---- layer 1 (msg writes relrow; weight precompute once) ----
  msg_kernel<<<msg_blocks, 256, 0, stream>>>(xb, WT1, eidx, wrel, msgp, relrow, nwaves);
  weight_kernel<<<agg_blocks, 256, 0, stream>>>(relrow, dstoff, wrow, N);
  agg_kernel<<<agg_blocks, 256, 0, stream>>>(msgp, dstoff, wrow, agg, N);
  selfloop_kernel<<<sl_blocks, 256, 0, stream>>>(xb, WTl1, agg, out, hb, N);

  // ---- layer 2 (wrow already valid) ----
  msg_kernel<<<msg_blocks, 256, 0, stream>>>(hb, WT2, eidx, wrel, msgp, nullptr, nwaves);
  agg_kernel<<<agg_blocks, 256, 0, stream>>>(msgp, dstoff, wrow, agg, N);
  selfloop_kernel<<<sl_blocks, 256, 0, stream>>>(hb, WTl2, agg, out, nullptr, N);
}